// Round 5
// baseline (3869.145 us; speedup 1.0000x reference)
//
#include <hip/hip_runtime.h>
#include <math.h>

#define B_ROWS 262144
#define GAMMA_C 1.3f
#define EPS_C 1e-5f
#define SQH_C 0.70710678118654752440f
#define SL_SCALE (1.0f/201326592.0f)   // 1/(3*B*256)

typedef _Float16 f16;
typedef f16 f16x8 __attribute__((ext_vector_type(8)));
typedef f16 f16x4 __attribute__((ext_vector_type(4)));
typedef float f32x4 __attribute__((ext_vector_type(4)));

// LDS pool layout (bytes)
#define OFF_SO  131072   // 16 KB epilogue out (64 rows x 256 B)
#define OFF_S1  147456
#define OFF_S2  148480
#define OFF_AF  149504
#define OFF_BF  150528
#define OFF_BA  151552
#define OFF_BB  152576
#define OFF_M0  153600
#define OFF_P0  154624
#define OFF_ENT 155648
#define SMEM_SZ 155712
#define OFF_Z   32768    // attention z-buffer: 64 rows x 1 KB (inside sA slot, att sA = 32 KB)

__device__ __forceinline__ int swzb(int row, int kb, int RB) {
  return row * RB + (kb ^ ((row & (((RB >> 4) - 1) & 31)) << 4));
}

// ---------------- bn0 ----------------
__global__ void bn0_accum(const float* __restrict__ x, float* __restrict__ sums) {
  const int col = threadIdx.x;
  const size_t r0 = (size_t)blockIdx.x * 128;
  float s1 = 0.f, s2 = 0.f;
  for (int i = 0; i < 128; ++i) {
    float v = x[(r0 + i) * 256 + col];
    s1 += v; s2 += v * v;
  }
  atomicAdd(&sums[col * 2], s1);
  atomicAdd(&sums[col * 2 + 1], s2);
}

__global__ void bn0_final(const float* __restrict__ sums, const float* __restrict__ g,
                          const float* __restrict__ b, float* __restrict__ bnA,
                          float* __restrict__ bnB) {
  int c = threadIdx.x;
  float mu = sums[c * 2] * (1.f / B_ROWS);
  float var = sums[c * 2 + 1] * (1.f / B_ROWS) - mu * mu;
  float a = rsqrtf(var + EPS_C) * g[c];
  bnA[c] = a;
  bnB[c] = b[c] - mu * a;
}

// ---------------- weight prep: f32 [K][256] -> f16 [256][K] ----------------
__global__ void wprep(const float* __restrict__ src, f16* __restrict__ dst, int K) {
  int idx = blockIdx.x * 256 + threadIdx.x;
  int n = idx / K, k = idx - n * K;
  dst[idx] = (f16)src[(size_t)k * 256 + n];
}

// ---------------- fused GLU phase (two-pass GEMM + ghost-BN + GLU) ----------------
template <int KD, int RESID, int DOUT>
__device__ __forceinline__ void glu_phase(
    char* __restrict__ P, const int tid, const int r0, const int s,
    const f16* __restrict__ Wt, const float* __restrict__ gv, const float* __restrict__ bv,
    const f16* __restrict__ MxG, float* __restrict__ dout,
    f16x8 (&hA)[16], f16x8 (&hB)[16])
{
  constexpr int KS = KD / 32;
  constexpr int RB = KD * 2;
  constexpr int RS = (KD == 256) ? 256 : 512;
  constexpr int NBLK = 1024 / RS;
  constexpr int NSC = RS / 16;
  const int w = tid >> 6, l = tid & 63, lg = l >> 4, lc = l & 15;
  char* sAc = P;
  char* sOc = P + OFF_SO;
  float* sS1 = (float*)(P + OFF_S1);
  float* sS2 = (float*)(P + OFF_S2);
  float* sAf = (float*)(P + OFF_AF);
  float* sBf = (float*)(P + OFF_BF);
  const int c1 = w * 16 + lc;

  // hoist W fragments for the wave's col-tile pair {w, w+8} (reused by both passes)
  f16x8 bf0[KS], bf1[KS];
#pragma unroll
  for (int ks = 0; ks < KS; ++ks) {
    bf0[ks] = *(const f16x8*)(Wt + (size_t)(w * 16 + lc) * KD + ks * 32 + lg * 8);
    bf1[ks] = *(const f16x8*)(Wt + (size_t)((w + 8) * 16 + lc) * KD + ks * 32 + lg * 8);
  }

  float st1a = 0.f, st2a = 0.f, st1b = 0.f, st2b = 0.f;
  // ---------------- pass 0: stats ----------------
  for (int blk = 0; blk < NBLK; ++blk) {
    __syncthreads();
    if (KD == 256) {
#pragma unroll 4
      for (int p = 0; p < 16; ++p) {
        int slot = p * 512 + tid;
        int rl = slot >> 5, kc = slot & 31;
        f16x8 v = *(const f16x8*)(MxG + (size_t)(r0 + blk * 256 + rl) * 256 + kc * 8);
        *(f16x8*)(sAc + swzb(rl, kc * 16, RB)) = v;
      }
    } else {
#pragma unroll
      for (int t2 = 0; t2 < 16; ++t2) {
        f16x8 v = (blk == 0) ? hA[t2] : hB[t2];
        *(f16x8*)(sAc + swzb(tid, t2 * 16, RB)) = v;
      }
    }
    __syncthreads();
#pragma unroll 2
    for (int sc = 0; sc < NSC; ++sc) {
      f32x4 a0 = {0.f,0.f,0.f,0.f}, a1 = {0.f,0.f,0.f,0.f};
#pragma unroll
      for (int ks = 0; ks < KS; ++ks) {
        f16x8 af = *(const f16x8*)(sAc + swzb(sc * 16 + lc, ks * 64 + lg * 16, RB));
        a0 = __builtin_amdgcn_mfma_f32_16x16x32_f16(af, bf0[ks], a0, 0, 0, 0);
        a1 = __builtin_amdgcn_mfma_f32_16x16x32_f16(af, bf1[ks], a1, 0, 0, 0);
      }
#pragma unroll
      for (int j = 0; j < 4; ++j) {
        st1a += a0[j]; st2a += a0[j] * a0[j];
        st1b += a1[j]; st2b += a1[j] * a1[j];
      }
    }
  }
  st1a += __shfl_xor(st1a, 16); st1a += __shfl_xor(st1a, 32);
  st2a += __shfl_xor(st2a, 16); st2a += __shfl_xor(st2a, 32);
  st1b += __shfl_xor(st1b, 16); st1b += __shfl_xor(st1b, 32);
  st2b += __shfl_xor(st2b, 16); st2b += __shfl_xor(st2b, 32);
  if (l < 16) {
    sS1[c1] = st1a; sS2[c1] = st2a;
    sS1[c1 + 128] = st1b; sS2[c1 + 128] = st2b;
  }
  __syncthreads();
  if (tid < 256) {
    float mu = sS1[tid] * (1.f / 1024.f);
    float var = sS2[tid] * (1.f / 1024.f) - mu * mu;
    float a = rsqrtf(var + EPS_C) * gv[tid];
    sAf[tid] = a; sBf[tid] = bv[tid] - mu * a;
  }
  __syncthreads();
  const float bA1 = sAf[c1], bO1 = sBf[c1];
  const float bA2 = sAf[c1 + 128], bO2 = sBf[c1 + 128];
  // ---------------- pass 1: apply (residual + dout in f32 at MFMA side) ----------------
  for (int blk = 0; blk < NBLK; ++blk) {
    __syncthreads();
    if (KD == 256) {
#pragma unroll 4
      for (int p = 0; p < 16; ++p) {
        int slot = p * 512 + tid;
        int rl = slot >> 5, kc = slot & 31;
        f16x8 v = *(const f16x8*)(MxG + (size_t)(r0 + blk * 256 + rl) * 256 + kc * 8);
        *(f16x8*)(sAc + swzb(rl, kc * 16, RB)) = v;
      }
    } else {
#pragma unroll
      for (int t2 = 0; t2 < 16; ++t2) {
        f16x8 v = (blk == 0) ? hA[t2] : hB[t2];
        *(f16x8*)(sAc + swzb(tid, t2 * 16, RB)) = v;
      }
    }
    __syncthreads();
    for (int g = 0; g < RS / 64; ++g) {
#pragma unroll
      for (int s4 = 0; s4 < 4; ++s4) {
        const int sc = g * 4 + s4;
        f32x4 a0 = {0.f,0.f,0.f,0.f}, a1 = {0.f,0.f,0.f,0.f};
#pragma unroll
        for (int ks = 0; ks < KS; ++ks) {
          f16x8 af = *(const f16x8*)(sAc + swzb(sc * 16 + lc, ks * 64 + lg * 16, RB));
          a0 = __builtin_amdgcn_mfma_f32_16x16x32_f16(af, bf0[ks], a0, 0, 0, 0);
          a1 = __builtin_amdgcn_mfma_f32_16x16x32_f16(af, bf1[ks], a1, 0, 0, 0);
        }
#pragma unroll
        for (int j = 0; j < 4; ++j) {
          float g1v = a0[j] * bA1 + bO1;
          float g2v = a1[j] * bA2 + bO2;
          float hv = g1v / (1.f + __expf(-g2v));
          const int rlt = sc * 16 + lg * 4 + j;        // row within blk tile
          if (RESID) {
            f16 hp = *(const f16*)(sAc + swzb(rlt, c1 * 2, RB));  // A-tile IS h_prev
            hv = (hv + (float)hp) * SQH_C;
          }
          if (DOUT && (c1 < 64)) {                      // wave-uniform (w<4)
            float rl = fmaxf(hv, 0.f);
            float* dp = dout + (size_t)(r0 + blk * RS + rlt) * 64 + c1;
            if (s == 0) *dp = rl; else *dp += rl;
          }
          const int rl64 = s4 * 16 + lg * 4 + j;
          *(f16*)(sOc + rl64 * 256 + ((c1 * 2) ^ ((rl64 & 15) << 4))) = (f16)hv;
        }
      }
      __syncthreads();
      const int G0 = blk * RS + g * 64;
      const int ro = (G0 < 512) ? (tid - G0) : (tid - (G0 - 512));
      if (ro >= 0 && ro < 64) {
#pragma unroll
        for (int t2 = 0; t2 < 16; ++t2) {
          f16x8 rd = *(const f16x8*)(sOc + ro * 256 + ((t2 * 16) ^ ((ro & 15) << 4)));
          if (G0 < 512) hA[t2] = rd; else hB[t2] = rd;
        }
      }
      __syncthreads();
    }
  }
}

// ---------------- fused attention + ghost-BN + sparsemax + masks/Mx/P1 ----------------
template <int SMODE>   // 1: prior = sP0 vector, write P1; 2: prior from P1 buffer
__device__ __forceinline__ void att_phase(
    char* __restrict__ P, const int tid, const int r0,
    const f16* __restrict__ Wt, const float* __restrict__ ga, const float* __restrict__ ba,
    const float* __restrict__ x, f16* __restrict__ P1, f16* __restrict__ MxG,
    float* __restrict__ mkS, f16x8 (&hA)[16], f16x8 (&hB)[16], float& entAcc)
{
  const int w = tid >> 6, l = tid & 63, lg = l >> 4, lc = l & 15;
  char* sAc = P;                 // 256 rows x 128 B
  char* sZc = P + OFF_Z;         // 64 rows x 1 KB
  float* sS1 = (float*)(P + OFF_S1);
  float* sS2 = (float*)(P + OFF_S2);
  float* sAf = (float*)(P + OFF_AF);
  float* sBf = (float*)(P + OFF_BF);
  float* sbA = (float*)(P + OFF_BA);
  float* sbB = (float*)(P + OFF_BB);
  float* sP0 = (float*)(P + OFF_P0);
  const int c1 = w * 16 + lc, c2 = c1 + 128;

  f16x8 bf0[2], bf1[2];
#pragma unroll
  for (int ks = 0; ks < 2; ++ks) {
    bf0[ks] = *(const f16x8*)(Wt + (size_t)(w * 16 + lc) * 64 + ks * 32 + lg * 8);
    bf1[ks] = *(const f16x8*)(Wt + (size_t)((w + 8) * 16 + lc) * 64 + ks * 32 + lg * 8);
  }
  float st1a = 0.f, st2a = 0.f, st1b = 0.f, st2b = 0.f;
  // pass 0: stats
  for (int blk = 0; blk < 4; ++blk) {
    __syncthreads();
    {
      const int idx = tid - (blk & 1) * 256;
      if (idx >= 0 && idx < 256) {
#pragma unroll
        for (int t2 = 8; t2 < 16; ++t2) {
          f16x8 v = (blk < 2) ? hA[t2] : hB[t2];
          *(f16x8*)(sAc + swzb(idx, (t2 - 8) * 16, 128)) = v;
        }
      }
    }
    __syncthreads();
#pragma unroll 2
    for (int sc = 0; sc < 16; ++sc) {
      f32x4 a0 = {0.f,0.f,0.f,0.f}, a1 = {0.f,0.f,0.f,0.f};
#pragma unroll
      for (int ks = 0; ks < 2; ++ks) {
        f16x8 af = *(const f16x8*)(sAc + swzb(sc * 16 + lc, ks * 64 + lg * 16, 128));
        a0 = __builtin_amdgcn_mfma_f32_16x16x32_f16(af, bf0[ks], a0, 0, 0, 0);
        a1 = __builtin_amdgcn_mfma_f32_16x16x32_f16(af, bf1[ks], a1, 0, 0, 0);
      }
#pragma unroll
      for (int j = 0; j < 4; ++j) {
        st1a += a0[j]; st2a += a0[j] * a0[j];
        st1b += a1[j]; st2b += a1[j] * a1[j];
      }
    }
  }
  st1a += __shfl_xor(st1a, 16); st1a += __shfl_xor(st1a, 32);
  st2a += __shfl_xor(st2a, 16); st2a += __shfl_xor(st2a, 32);
  st1b += __shfl_xor(st1b, 16); st1b += __shfl_xor(st1b, 32);
  st2b += __shfl_xor(st2b, 16); st2b += __shfl_xor(st2b, 32);
  if (l < 16) {
    sS1[c1] = st1a; sS2[c1] = st2a;
    sS1[c1 + 128] = st1b; sS2[c1 + 128] = st2b;
  }
  __syncthreads();
  if (tid < 256) {
    float mu = sS1[tid] * (1.f / 1024.f);
    float var = sS2[tid] * (1.f / 1024.f) - mu * mu;
    float a = rsqrtf(var + EPS_C) * ga[tid];
    sAf[tid] = a; sBf[tid] = ba[tid] - mu * a;
  }
  __syncthreads();
  const float aA1 = sAf[c1], aO1 = sBf[c1], aA2 = sAf[c2], aO2 = sBf[c2];
  float pv1 = 0.f, pv2 = 0.f;
  if (SMODE == 1) { pv1 = sP0[c1]; pv2 = sP0[c2]; }
  // pass 1: apply + sparsemax
  for (int blk = 0; blk < 4; ++blk) {
    __syncthreads();
    {
      const int idx = tid - (blk & 1) * 256;
      if (idx >= 0 && idx < 256) {
#pragma unroll
        for (int t2 = 8; t2 < 16; ++t2) {
          f16x8 v = (blk < 2) ? hA[t2] : hB[t2];
          *(f16x8*)(sAc + swzb(idx, (t2 - 8) * 16, 128)) = v;
        }
      }
    }
    __syncthreads();
    for (int g = 0; g < 4; ++g) {
#pragma unroll
      for (int s4 = 0; s4 < 4; ++s4) {
        const int sc = g * 4 + s4;
        f32x4 a0 = {0.f,0.f,0.f,0.f}, a1 = {0.f,0.f,0.f,0.f};
#pragma unroll
        for (int ks = 0; ks < 2; ++ks) {
          f16x8 af = *(const f16x8*)(sAc + swzb(sc * 16 + lc, ks * 64 + lg * 16, 128));
          a0 = __builtin_amdgcn_mfma_f32_16x16x32_f16(af, bf0[ks], a0, 0, 0, 0);
          a1 = __builtin_amdgcn_mfma_f32_16x16x32_f16(af, bf1[ks], a1, 0, 0, 0);
        }
#pragma unroll
        for (int j = 0; j < 4; ++j) {
          const int rloc = s4 * 16 + lg * 4 + j;
          const size_t rg = (size_t)(r0 + blk * 256 + g * 64 + rloc);
          float z1 = a0[j] * aA1 + aO1;
          float z2 = a1[j] * aA2 + aO2;
          if (SMODE == 1) { z1 *= pv1; z2 *= pv2; }
          else {
            z1 *= (float)P1[rg * 256 + c1];
            z2 *= (float)P1[rg * 256 + c2];
          }
          *(float*)(sZc + rloc * 1024 + ((c1 * 4) ^ ((rloc & 31) << 4))) = z1;
          *(float*)(sZc + rloc * 1024 + ((c2 * 4) ^ ((rloc & 31) << 4))) = z2;
        }
      }
      __syncthreads();
#pragma unroll
      for (int rr = 0; rr < 2; ++rr) {
        const int rloc = rr * 32 + w * 4 + lg;
        const size_t rg = (size_t)(r0 + blk * 256 + g * 64 + rloc);
        f32x4 zz[4];
#pragma unroll
        for (int q = 0; q < 4; ++q)
          zz[q] = *(const f32x4*)(sZc + rloc * 1024 + (((lc * 64) + q * 16) ^ ((rloc & 31) << 4)));
        float m = zz[0][0];
#pragma unroll
        for (int q = 0; q < 4; ++q)
#pragma unroll
          for (int e = 0; e < 4; ++e) m = fmaxf(m, zz[q][e]);
#pragma unroll
        for (int d = 1; d < 16; d <<= 1) m = fmaxf(m, __shfl_xor(m, d));
        float lo = m - 1.f, hi = m;
        for (int it = 0; it < 20; ++it) {
          float tau = 0.5f * (lo + hi);
          float ss = 0.f;
#pragma unroll
          for (int q = 0; q < 4; ++q)
#pragma unroll
            for (int e = 0; e < 4; ++e) ss += fmaxf(zz[q][e] - tau, 0.f);
#pragma unroll
          for (int d = 1; d < 16; d <<= 1) ss += __shfl_xor(ss, d);
          if (ss > 1.f) lo = tau; else hi = tau;
        }
        const float tau = 0.5f * (lo + hi);
        f32x4 xv[4];
#pragma unroll
        for (int q = 0; q < 4; ++q) xv[q] = *(const f32x4*)(x + rg * 256 + lc * 16 + q * 4);
        float* mp = mkS + rg * 256 + lc * 16;
        f16x8 mxa, mxb, p1a, p1b;
        float entp = 0.f;
#pragma unroll
        for (int q = 0; q < 4; ++q) {
#pragma unroll
          for (int e = 0; e < 4; ++e) {
            const int k = q * 4 + e;
            const int c = lc * 16 + k;
            float M = fmaxf(zz[q][e] - tau, 0.f);
            mp[k] = M;
            entp -= M * __logf(M + 1e-15f);
            float mxv = M * (xv[q][e] * sbA[c] + sbB[c]);
            if (k < 8) mxa[k] = (f16)mxv; else mxb[k - 8] = (f16)mxv;
            if (SMODE == 1) {
              float pv = sP0[c] * (GAMMA_C - M);
              if (k < 8) p1a[k] = (f16)pv; else p1b[k - 8] = (f16)pv;
            }
          }
        }
        entAcc += entp;
        *(f16x8*)(MxG + rg * 256 + lc * 16) = mxa;
        *(f16x8*)(MxG + rg * 256 + lc * 16 + 8) = mxb;
        if (SMODE == 1) {
          *(f16x8*)(P1 + rg * 256 + lc * 16) = p1a;
          *(f16x8*)(P1 + rg * 256 + lc * 16 + 8) = p1b;
        }
      }
      __syncthreads();
    }
  }
}

// ---------------- the mega kernel: one WG per VB, all 3 steps ----------------
__global__ __launch_bounds__(512, 2) void mega(
    const float* __restrict__ x, const float* __restrict__ bnA, const float* __restrict__ bnB,
    const f16* __restrict__ wAtt, const f16* __restrict__ wSh0, const f16* __restrict__ wSh1,
    const f16* __restrict__ wSt,
    const float* __restrict__ gsh0, const float* __restrict__ bsh0,
    const float* __restrict__ gsh1, const float* __restrict__ bsh1,
    const float* __restrict__ gstep, const float* __restrict__ bstep,
    const float* __restrict__ gatt, const float* __restrict__ batt,
    f16* __restrict__ P1, f16* __restrict__ MxG,
    float* __restrict__ masks, float* __restrict__ dout, float* __restrict__ slpart)
{
  __shared__ __align__(16) char P[SMEM_SZ];
  const int tid = threadIdx.x;
  const int w = tid >> 6, l = tid & 63;
  const int r0 = blockIdx.x << 10;
  float* sbA = (float*)(P + OFF_BA);
  float* sbB = (float*)(P + OFF_BB);
  float* sM0 = (float*)(P + OFF_M0);
  float* sP0 = (float*)(P + OFF_P0);
  float* sEnt = (float*)(P + OFF_ENT);
  f16x8 hA[16], hB[16];
  {
    f16x8 zv;
#pragma unroll
    for (int e = 0; e < 8; ++e) zv[e] = (f16)0.f;
#pragma unroll
    for (int t = 0; t < 16; ++t) { hA[t] = zv; hB[t] = zv; }
  }
  float entAcc = 0.f;
  if (tid < 256) { sbA[tid] = bnA[tid]; sbB[tid] = bnB[tid]; }

  for (int s = 0; s < 3; ++s) {
    float* mkS = masks + (size_t)s * B_ROWS * 256;
    if (s == 0) {
      // step-0 mask is one broadcast vector: sparsemax(batt)
      if (w == 0) {
        float z0 = batt[l * 4], z1 = batt[l * 4 + 1], z2 = batt[l * 4 + 2], z3 = batt[l * 4 + 3];
        float m = fmaxf(fmaxf(z0, z1), fmaxf(z2, z3));
#pragma unroll
        for (int d = 1; d < 64; d <<= 1) m = fmaxf(m, __shfl_xor(m, d));
        float lo = m - 1.f, hi = m;
        for (int it = 0; it < 24; ++it) {
          float tau = 0.5f * (lo + hi);
          float ss = fmaxf(z0 - tau, 0.f) + fmaxf(z1 - tau, 0.f) +
                     fmaxf(z2 - tau, 0.f) + fmaxf(z3 - tau, 0.f);
#pragma unroll
          for (int d = 1; d < 64; d <<= 1) ss += __shfl_xor(ss, d);
          if (ss > 1.f) lo = tau; else hi = tau;
        }
        float tau = 0.5f * (lo + hi);
        float zz[4] = {z0, z1, z2, z3};
        float entp = 0.f;
#pragma unroll
        for (int e = 0; e < 4; ++e) {
          float M = fmaxf(zz[e] - tau, 0.f);
          sM0[l * 4 + e] = M;
          sP0[l * 4 + e] = GAMMA_C - M;
          entp -= M * __logf(M + 1e-15f);
        }
        entAcc += 1024.f * entp;
      }
      __syncthreads();
      float M0v[4], bA0[4], bB0[4];
#pragma unroll
      for (int e = 0; e < 4; ++e) {
        M0v[e] = sM0[l * 4 + e];
        bA0[e] = sbA[l * 4 + e];
        bB0[e] = sbB[l * 4 + e];
      }
      for (int rr = 0; rr < 128; ++rr) {
        const int rloc = w * 128 + rr;
        const size_t rg = (size_t)(r0 + rloc);
        f32x4 xv = *(const f32x4*)(x + rg * 256 + l * 4);
        float* mp = mkS + rg * 256 + l * 4;
        f16x4 mx;
#pragma unroll
        for (int e = 0; e < 4; ++e) {
          mp[e] = M0v[e];
          mx[e] = (f16)(M0v[e] * (xv[e] * bA0[e] + bB0[e]));
        }
        *(f16x4*)(MxG + rg * 256 + l * 4) = mx;
      }
    } else if (s == 1) {
      att_phase<1>(P, tid, r0, wAtt, gatt + 256, batt + 256, x, P1, MxG, mkS, hA, hB, entAcc);
    } else {
      att_phase<2>(P, tid, r0, wAtt + 256 * 64, gatt + 512, batt + 512, x, P1, MxG, mkS, hA, hB, entAcc);
    }
    glu_phase<256, 0, 0>(P, tid, r0, s, wSh0, gsh0, bsh0, MxG, nullptr, hA, hB);
    glu_phase<128, 1, 0>(P, tid, r0, s, wSh1, gsh1, bsh1, nullptr, nullptr, hA, hB);
    glu_phase<128, 1, 0>(P, tid, r0, s, wSt + (size_t)(s * 2) * 256 * 128,
                         gstep + (s * 2) * 256, bstep + (s * 2) * 256, nullptr, nullptr, hA, hB);
    glu_phase<128, 1, 1>(P, tid, r0, s, wSt + (size_t)(s * 2 + 1) * 256 * 128,
                         gstep + (s * 2 + 1) * 256, bstep + (s * 2 + 1) * 256, nullptr, dout, hA, hB);
  }
#pragma unroll
  for (int d = 1; d < 64; d <<= 1) entAcc += __shfl_xor(entAcc, d);
  if (l == 0) sEnt[w] = entAcc;
  __syncthreads();
  if (tid == 0) {
    float t = 0.f;
#pragma unroll
    for (int i = 0; i < 8; ++i) t += sEnt[i];
    slpart[blockIdx.x] = t;
  }
}

__global__ void sl_final(const float* __restrict__ part, float* __restrict__ out) {
  __shared__ float sm[256];
  sm[threadIdx.x] = part[threadIdx.x];
  __syncthreads();
  for (int d = 128; d > 0; d >>= 1) {
    if ((int)threadIdx.x < d) sm[threadIdx.x] += sm[threadIdx.x + d];
    __syncthreads();
  }
  if (threadIdx.x == 0) out[0] = sm[0] * SL_SCALE;
}

// ---------------- host ----------------
extern "C" void kernel_launch(void* const* d_in, const int* in_sizes, int n_in,
                              void* d_out, int out_size, void* d_ws, size_t ws_size,
                              hipStream_t stream) {
  (void)in_sizes; (void)n_in; (void)out_size; (void)ws_size;
  const float* x    = (const float*)d_in[0];
  const float* bn0g = (const float*)d_in[1];
  const float* bn0b = (const float*)d_in[2];
  const float* Wsh0 = (const float*)d_in[3];
  const float* gsh0 = (const float*)d_in[4];
  const float* bsh0 = (const float*)d_in[5];
  const float* Wsh1 = (const float*)d_in[6];
  const float* gsh1 = (const float*)d_in[7];
  const float* bsh1 = (const float*)d_in[8];
  const float* Wstep = (const float*)d_in[9];
  const float* gstep = (const float*)d_in[10];
  const float* bstep = (const float*)d_in[11];
  const float* Watt = (const float*)d_in[12];
  const float* gatt = (const float*)d_in[13];
  const float* batt = (const float*)d_in[14];

  float* dout = (float*)d_out;
  float* slo = dout + (size_t)B_ROWS * 64;
  float* masks = slo + 1;

  char* ws = (char*)d_ws;
  size_t off = 0;
  auto carve = [&](size_t bytes) -> char* {
    char* p = ws + off;
    off += (bytes + 255) & ~(size_t)255;
    return p;
  };
  f16* wt_att   = (f16*)carve((size_t)2 * 256 * 64 * 2);
  f16* wt_sh0   = (f16*)carve((size_t)256 * 256 * 2);
  f16* wt_sh1   = (f16*)carve((size_t)256 * 128 * 2);
  f16* wt_step  = (f16*)carve((size_t)6 * 256 * 128 * 2);
  float* bn0sum = (float*)carve(512 * 4);
  float* bnA    = (float*)carve(256 * 4);
  float* bnB    = (float*)carve(256 * 4);
  float* slpart = (float*)carve(256 * 4);
  f16* P1       = (f16*)carve((size_t)B_ROWS * 256 * 2);
  f16* Mx       = (f16*)carve((size_t)B_ROWS * 256 * 2);

  hipMemsetAsync(bn0sum, 0, 512 * 4, stream);
  bn0_accum<<<2048, 256, 0, stream>>>(x, bn0sum);
  bn0_final<<<1, 256, 0, stream>>>(bn0sum, bn0g, bn0b, bnA, bnB);
  for (int s = 1; s < 3; ++s)
    wprep<<<64, 256, 0, stream>>>(Watt + (size_t)s * 64 * 256, wt_att + (size_t)(s - 1) * 256 * 64, 64);
  wprep<<<256, 256, 0, stream>>>(Wsh0, wt_sh0, 256);
  wprep<<<128, 256, 0, stream>>>(Wsh1, wt_sh1, 128);
  for (int i = 0; i < 6; ++i)
    wprep<<<128, 256, 0, stream>>>(Wstep + (size_t)i * 128 * 256, wt_step + (size_t)i * 256 * 128, 128);

  mega<<<256, 512, 0, stream>>>(x, bnA, bnB, wt_att, wt_sh0, wt_sh1, wt_step,
                                gsh0, bsh0, gsh1, bsh1, gstep, bstep, gatt, batt,
                                P1, Mx, masks, dout, slpart);
  sl_final<<<1, 256, 0, stream>>>(slpart, slo);
}